// Round 7
// baseline (8486.211 us; speedup 1.0000x reference)
//
#include <hip/hip_runtime.h>
#include <hip/hip_bf16.h>
#include <math.h>

typedef __bf16 bf16_t;
typedef bf16_t bf16x8 __attribute__((ext_vector_type(8)));

// ---------------------------------------------------------------------------
// LayerNorm, fp32 input -> bf16 output. One 256-thread block per row of 1024.
// ---------------------------------------------------------------------------
__global__ __launch_bounds__(256) void ln_f32(const float* __restrict__ x,
                                              const float* __restrict__ g,
                                              const float* __restrict__ b,
                                              bf16_t* __restrict__ y) {
  const int D = 1024;
  int row = blockIdx.x;
  int t = threadIdx.x;
  const float* xr = x + (size_t)row * D + t * 4;
  float x0 = xr[0], x1 = xr[1], x2 = xr[2], x3 = xr[3];
  float sum = x0 + x1 + x2 + x3;
  float sq = x0 * x0 + x1 * x1 + x2 * x2 + x3 * x3;
  for (int d = 32; d; d >>= 1) {
    sum += __shfl_down(sum, d);
    sq += __shfl_down(sq, d);
  }
  __shared__ float ssum[4], ssq[4];
  int w = t >> 6, lane = t & 63;
  if (lane == 0) { ssum[w] = sum; ssq[w] = sq; }
  __syncthreads();
  float ts = ssum[0] + ssum[1] + ssum[2] + ssum[3];
  float tq = ssq[0] + ssq[1] + ssq[2] + ssq[3];
  float mean = ts * (1.0f / 1024.0f);
  float var = tq * (1.0f / 1024.0f) - mean * mean;
  float rstd = rsqrtf(var + 1e-5f);
  bf16_t* yr = y + (size_t)row * D + t * 4;
  const float* gr = g + t * 4;
  const float* br = b + t * 4;
  yr[0] = (bf16_t)((x0 - mean) * rstd * gr[0] + br[0]);
  yr[1] = (bf16_t)((x1 - mean) * rstd * gr[1] + br[1]);
  yr[2] = (bf16_t)((x2 - mean) * rstd * gr[2] + br[2]);
  yr[3] = (bf16_t)((x3 - mean) * rstd * gr[3] + br[3]);
}

// LayerNorm, bf16 input -> bf16 output.
__global__ __launch_bounds__(256) void ln_bf16(const bf16_t* __restrict__ x,
                                               const float* __restrict__ g,
                                               const float* __restrict__ b,
                                               bf16_t* __restrict__ y) {
  const int D = 1024;
  int row = blockIdx.x;
  int t = threadIdx.x;
  const bf16_t* xr = x + (size_t)row * D + t * 4;
  float x0 = (float)xr[0], x1 = (float)xr[1], x2 = (float)xr[2], x3 = (float)xr[3];
  float sum = x0 + x1 + x2 + x3;
  float sq = x0 * x0 + x1 * x1 + x2 * x2 + x3 * x3;
  for (int d = 32; d; d >>= 1) {
    sum += __shfl_down(sum, d);
    sq += __shfl_down(sq, d);
  }
  __shared__ float ssum[4], ssq[4];
  int w = t >> 6, lane = t & 63;
  if (lane == 0) { ssum[w] = sum; ssq[w] = sq; }
  __syncthreads();
  float ts = ssum[0] + ssum[1] + ssum[2] + ssum[3];
  float tq = ssq[0] + ssq[1] + ssq[2] + ssq[3];
  float mean = ts * (1.0f / 1024.0f);
  float var = tq * (1.0f / 1024.0f) - mean * mean;
  float rstd = rsqrtf(var + 1e-5f);
  bf16_t* yr = y + (size_t)row * D + t * 4;
  const float* gr = g + t * 4;
  const float* br = b + t * 4;
  yr[0] = (bf16_t)((x0 - mean) * rstd * gr[0] + br[0]);
  yr[1] = (bf16_t)((x1 - mean) * rstd * gr[1] + br[1]);
  yr[2] = (bf16_t)((x2 - mean) * rstd * gr[2] + br[2]);
  yr[3] = (bf16_t)((x3 - mean) * rstd * gr[3] + br[3]);
}

// ---------------------------------------------------------------------------
// LoRA first stage: t[M,4] = h[M,K] @ la[4,K]^T. h bf16, la fp32, t fp32.
// One wave per row.
// ---------------------------------------------------------------------------
__global__ __launch_bounds__(256) void lora_t_kernel(const bf16_t* __restrict__ h,
                                                     const float* __restrict__ la,
                                                     float* __restrict__ t, int K) {
  int lane = threadIdx.x & 63;
  int w = threadIdx.x >> 6;
  int row = blockIdx.x * 4 + w;
  const bf16_t* hrow = h + (size_t)row * K;
  float acc[4] = {0.f, 0.f, 0.f, 0.f};
  for (int it = 0; it < K / 512; ++it) {
    int base = it * 512 + lane * 8;
    bf16x8 hx = *(const bf16x8*)(hrow + base);
#pragma unroll
    for (int r = 0; r < 4; ++r) {
      const float* ar = la + (size_t)r * K + base;
#pragma unroll
      for (int j = 0; j < 8; ++j) acc[r] += (float)hx[j] * ar[j];
    }
  }
#pragma unroll
  for (int r = 0; r < 4; ++r) {
    for (int d = 32; d; d >>= 1) acc[r] += __shfl_down(acc[r], d);
  }
  if (lane == 0) {
#pragma unroll
    for (int r = 0; r < 4; ++r) t[(size_t)row * 4 + r] = acc[r];
  }
}

// ---------------------------------------------------------------------------
// Simple tiled VALU GEMM: C[M,N] = epi(A[M,K] @ Brows[N, ldb]^T slice).
// A bf16 (row stride K), B fp32 (row stride ldb; pass B+koff for col offset).
// Output: Cf (fp32) if non-null, else Cb (bf16). 64x64 tile, BK=16,
// 256 threads, 4x4 per thread.
// epi: (+bias) (+0.25 * t[M,4]@lb[N,4]^T) (gelu?) (+residf fp32 / residb bf16)
// NOTE: residf/Cf intentionally NOT __restrict__ (step 9b reads+writes d_out).
// ---------------------------------------------------------------------------
__global__ __launch_bounds__(256) void gemm_simple(
    const bf16_t* __restrict__ A, const float* __restrict__ B,
    const float* __restrict__ bias, const float* __restrict__ loraT,
    const float* __restrict__ loraB, const float* residf,
    const bf16_t* __restrict__ residb, bf16_t* Cb, float* Cf,
    int M, int N, int K, int ldb, int dogelu) {
  __shared__ float As[16][65];
  __shared__ float Bs[16][65];
  int tid = threadIdx.x;
  int tx = tid & 15, ty = tid >> 4;
  int m0 = blockIdx.y * 64, n0 = blockIdx.x * 64;
  float acc[4][4] = {{0}};
  for (int k0 = 0; k0 < K; k0 += 16) {
#pragma unroll
    for (int l = 0; l < 4; ++l) {
      int idx = l * 256 + tid;
      int row = idx >> 4, kk = idx & 15;
      As[kk][row] = (float)A[(size_t)(m0 + row) * K + k0 + kk];
      Bs[kk][row] = B[(size_t)(n0 + row) * ldb + k0 + kk];
    }
    __syncthreads();
#pragma unroll
    for (int kk = 0; kk < 16; ++kk) {
      float a0 = As[kk][ty * 4 + 0], a1 = As[kk][ty * 4 + 1];
      float a2 = As[kk][ty * 4 + 2], a3 = As[kk][ty * 4 + 3];
      float b0 = Bs[kk][tx * 4 + 0], b1 = Bs[kk][tx * 4 + 1];
      float b2 = Bs[kk][tx * 4 + 2], b3 = Bs[kk][tx * 4 + 3];
      acc[0][0] += a0 * b0; acc[0][1] += a0 * b1; acc[0][2] += a0 * b2; acc[0][3] += a0 * b3;
      acc[1][0] += a1 * b0; acc[1][1] += a1 * b1; acc[1][2] += a1 * b2; acc[1][3] += a1 * b3;
      acc[2][0] += a2 * b0; acc[2][1] += a2 * b1; acc[2][2] += a2 * b2; acc[2][3] += a2 * b3;
      acc[3][0] += a3 * b0; acc[3][1] += a3 * b1; acc[3][2] += a3 * b2; acc[3][3] += a3 * b3;
    }
    __syncthreads();
  }
#pragma unroll
  for (int i = 0; i < 4; ++i) {
    int row = m0 + ty * 4 + i;
#pragma unroll
    for (int j = 0; j < 4; ++j) {
      int col = n0 + tx * 4 + j;
      float val = acc[i][j];
      if (bias) val += bias[col];
      if (loraT) {
        const float* tp = loraT + (size_t)row * 4;
        const float* lb = loraB + (size_t)col * 4;
        val += 0.25f * (tp[0] * lb[0] + tp[1] * lb[1] + tp[2] * lb[2] + tp[3] * lb[3]);
      }
      if (dogelu) val = 0.5f * val * (1.0f + erff(val * 0.70710678118654752f));
      if (residf) val += residf[(size_t)row * N + col];
      if (residb) val += (float)residb[(size_t)row * N + col];
      if (Cf) Cf[(size_t)row * N + col] = val;
      else Cb[(size_t)row * N + col] = (bf16_t)val;
    }
  }
}

// ---------------------------------------------------------------------------
// Simple attention: one block per (q_row, head, batch). Full softmax over
// S=1024 keys in LDS. q,k stored UNSCALED; dot scaled by hd^-0.5 = 0.125.
// ---------------------------------------------------------------------------
__global__ __launch_bounds__(256) void attn_simple(const bf16_t* __restrict__ q,
                                                   const bf16_t* __restrict__ k,
                                                   const bf16_t* __restrict__ v,
                                                   bf16_t* __restrict__ wv) {
  const int S = 1024, D = 1024;
  int qrow = blockIdx.x, h = blockIdx.y, b = blockIdx.z;
  int tid = threadIdx.x, lane = tid & 63, wid = tid >> 6;
  __shared__ float qv[64];
  __shared__ float s[1024];
  __shared__ float rmax[4], rsum[4];
  __shared__ float pv[4][64];
  size_t qoff = ((size_t)b * S + qrow) * D + (size_t)h * 64;
  if (tid < 64) qv[tid] = (float)q[qoff + tid];
  __syncthreads();
  float loc[4];
#pragma unroll
  for (int c = 0; c < 4; ++c) {
    int kk = c * 256 + tid;
    const bf16_t* kr = k + ((size_t)b * S + kk) * D + (size_t)h * 64;
    float dot = 0.f;
    for (int d = 0; d < 64; ++d) dot += qv[d] * (float)kr[d];
    loc[c] = dot * 0.125f;  // (hd^-0.25)^2
  }
  float m = fmaxf(fmaxf(loc[0], loc[1]), fmaxf(loc[2], loc[3]));
  for (int d = 32; d; d >>= 1) m = fmaxf(m, __shfl_down(m, d));
  if (lane == 0) rmax[wid] = m;
  __syncthreads();
  m = fmaxf(fmaxf(rmax[0], rmax[1]), fmaxf(rmax[2], rmax[3]));
  float psum = 0.f;
#pragma unroll
  for (int c = 0; c < 4; ++c) {
    int kk = c * 256 + tid;
    float e = __expf(loc[c] - m);
    s[kk] = e;
    psum += e;
  }
  for (int d = 32; d; d >>= 1) psum += __shfl_down(psum, d);
  if (lane == 0) rsum[wid] = psum;
  __syncthreads();  // also makes s[] visible to all
  float inv = 1.0f / (rsum[0] + rsum[1] + rsum[2] + rsum[3]);
  int d = tid & 63, c = tid >> 6;
  float part = 0.f;
  for (int kk = c * 256; kk < c * 256 + 256; ++kk)
    part += s[kk] * (float)v[((size_t)b * S + kk) * D + (size_t)h * 64 + d];
  pv[c][d] = part;
  __syncthreads();
  if (tid < 64) {
    float o = (pv[0][tid] + pv[1][tid] + pv[2][tid] + pv[3][tid]) * inv;
    wv[qoff + tid] = (bf16_t)o;
  }
}

// ---------------------------------------------------------------------------
extern "C" void kernel_launch(void* const* d_in, const int* in_sizes, int n_in,
                              void* d_out, int out_size, void* d_ws, size_t ws_size,
                              hipStream_t stream) {
  const int B = 8, S = 1024, D = 1024, F = 4096, H = 16;
  const int M = B * S;  // 8192

  // Inputs: setup_inputs() dict order, all float32 (per harness doc).
  const float* x = (const float*)d_in[0];
  const float* Wq = (const float*)d_in[1];
  const float* bq = (const float*)d_in[2];
  const float* Wk = (const float*)d_in[3];
  const float* Wv = (const float*)d_in[4];
  const float* bv = (const float*)d_in[5];
  const float* Wo = (const float*)d_in[6];
  const float* bo = (const float*)d_in[7];
  const float* la_k = (const float*)d_in[8];
  const float* lb_k = (const float*)d_in[9];
  const float* la_v = (const float*)d_in[10];
  const float* lb_v = (const float*)d_in[11];
  const float* la_o = (const float*)d_in[12];
  const float* lb_o = (const float*)d_in[13];
  const float* g_attn = (const float*)d_in[14];
  const float* b_attn = (const float*)d_in[15];
  const float* W1 = (const float*)d_in[16];
  const float* b1 = (const float*)d_in[17];
  const float* W2 = (const float*)d_in[18];
  const float* b2 = (const float*)d_in[19];
  const float* g_mlp = (const float*)d_in[20];
  const float* b_mlp = (const float*)d_in[21];

  // ---- workspace: 64.4 MiB total ----
  // [16B pad][t_k][t_v][t_o fp32, 384KB] [A][B][C][D] (16 MiB each, bf16 [M,D])
  float* t_k = (float*)((char*)d_ws + 16);
  float* t_v = t_k + (size_t)M * 4;
  float* t_o = t_v + (size_t)M * 4;
  const size_t MD = (size_t)M * D;  // 8,388,608 elems
  bf16_t* Abuf = (bf16_t*)((char*)d_ws + 409600);
  bf16_t* Bbuf = Abuf + MD;
  bf16_t* Cbuf = Abuf + 2 * MD;
  bf16_t* Dbuf = Abuf + 3 * MD;
  bf16_t* wvbuf = (bf16_t*)d_out;  // d_out (fp32-sized, 33.6MB) as bf16 scratch for wv
  float* outf = (float*)d_out;     // final output: FLOAT32 (reference output dtype)
  bf16_t* ubuf = Cbuf;             // u half: [M, 2048] = 2*MD elems = C∪D

  // 1. h = LN(x) -> A
  ln_f32<<<M, 256, 0, stream>>>(x, g_attn, b_attn, Abuf);
  // 2. LoRA t for k, v (from h)
  lora_t_kernel<<<M / 4, 256, 0, stream>>>(Abuf, la_k, t_k, D);
  lora_t_kernel<<<M / 4, 256, 0, stream>>>(Abuf, la_v, t_v, D);
  // 3. q -> B, k -> C, v -> D (unscaled; attention applies hd^-0.5 to scores)
  gemm_simple<<<dim3(16, 128), 256, 0, stream>>>(
      Abuf, Wq, bq, nullptr, nullptr, nullptr, nullptr, Bbuf, nullptr, M, D, D, D, 0);
  gemm_simple<<<dim3(16, 128), 256, 0, stream>>>(
      Abuf, Wk, nullptr, t_k, lb_k, nullptr, nullptr, Cbuf, nullptr, M, D, D, D, 0);
  gemm_simple<<<dim3(16, 128), 256, 0, stream>>>(
      Abuf, Wv, bv, t_v, lb_v, nullptr, nullptr, Dbuf, nullptr, M, D, D, D, 0);
  // 4. attention -> wv (bf16, in d_out scratch)
  attn_simple<<<dim3(S, H, B), 256, 0, stream>>>(Bbuf, Cbuf, Dbuf, wvbuf);
  // 5. LoRA t for o (input is wv)
  lora_t_kernel<<<M / 4, 256, 0, stream>>>(wvbuf, la_o, t_o, D);
  // 6. x1 = x + wv @ Wo^T + bo + lora_o -> B (q dead), bf16
  gemm_simple<<<dim3(16, 128), 256, 0, stream>>>(
      wvbuf, Wo, bo, t_o, lb_o, x, nullptr, Bbuf, nullptr, M, D, D, D, 0);
  // 7. h2 = LN(x1) -> A (h dead)
  ln_bf16<<<M, 256, 0, stream>>>(Bbuf, g_mlp, b_mlp, Abuf);
  // 8a. u_lo = gelu(h2 @ W1[0:2048]^T + b1[0:2048]) -> C∪D (k,v dead)
  gemm_simple<<<dim3(32, 128), 256, 0, stream>>>(
      Abuf, W1, b1, nullptr, nullptr, nullptr, nullptr, ubuf, nullptr, M, 2048, D, D, 1);
  // 9a. out = x1 + u_lo @ W2[:,0:2048]^T + b2  (FP32; full overwrite of d_out,
  //     wv scratch dead)
  gemm_simple<<<dim3(16, 128), 256, 0, stream>>>(
      ubuf, W2, b2, nullptr, nullptr, nullptr, Bbuf, nullptr, outf, M, D, 2048, F, 0);
  // 8b. u_hi = gelu(h2 @ W1[2048:4096]^T + b1[2048:4096]) -> C∪D
  gemm_simple<<<dim3(32, 128), 256, 0, stream>>>(
      Abuf, W1 + (size_t)2048 * D, b1 + 2048, nullptr, nullptr, nullptr, nullptr,
      ubuf, nullptr, M, 2048, D, D, 1);
  // 9b. out += u_hi @ W2[:,2048:4096]^T  (fp32 self-accumulate on d_out)
  gemm_simple<<<dim3(16, 128), 256, 0, stream>>>(
      ubuf, W2 + 2048, nullptr, nullptr, nullptr, outf, nullptr, nullptr, outf,
      M, D, 2048, F, 0);
}